// Round 3
// baseline (106.912 us; speedup 1.0000x reference)
//
#include <hip/hip_runtime.h>
#include <hip/hip_bf16.h>

#define BB 64
#define TT 512
#define HH 256
#define EE 128
#define VV 32000
#define SS 128
#define LL 16

typedef __attribute__((ext_vector_type(8))) short bf16x8;
typedef __attribute__((ext_vector_type(4))) float f32x4;

static __device__ __forceinline__ unsigned short f2bf(float x) {
    unsigned int u = __float_as_uint(x);
    unsigned int r = (u + 0x7fffu + ((u >> 16) & 1u)) >> 16;
    return (unsigned short)r;
}

// ---------- K1: fused {hW, prep_b, embed} partitioned by blockIdx ----------
// blocks 0..63   : hW[b,h] = attn_b[h] + last_hidden[b,:] . attn_W[h,0:H]
// blocks 64..95  : swizzle attn_W[:,H:2H] -> bf16 MFMA B-fragments
// blocks 96..159 : embed[b,:] = e + e @ ctrl_W.T + ctrl_b
__global__ __launch_bounds__(256) void k_pre(const float* __restrict__ last_hidden,
                                             const float* __restrict__ attn_W,
                                             const float* __restrict__ attn_b,
                                             const int* __restrict__ z_tm1,
                                             const float* __restrict__ emb_W,
                                             const float* __restrict__ ctrl_W,
                                             const float* __restrict__ ctrl_b,
                                             float* __restrict__ hW,
                                             float* __restrict__ embed,
                                             unsigned short* __restrict__ Bs) {
    __shared__ float sh[HH];
    int blk = blockIdx.x;
    int tid = threadIdx.x;
    if (blk < 64) {
        int b = blk, h = tid;
        sh[h] = last_hidden[b * HH + h];
        __syncthreads();
        const float4* wrow = (const float4*)(attn_W + (size_t)h * (2 * HH));
        float acc = attn_b[h];
        for (int k4 = 0; k4 < HH / 4; ++k4) {
            float4 w = wrow[k4];
            acc += sh[k4*4+0]*w.x + sh[k4*4+1]*w.y + sh[k4*4+2]*w.z + sh[k4*4+3]*w.w;
        }
        hW[b * HH + h] = acc;
    } else if (blk < 96) {
        // Bs layout: [kstep 0..7][tile 0..15][lane 0..63][8 bf16]
        // col = tile*16 + (lane&15), k = kstep*32 + (lane>>4)*8 + j
        int idx = (blk - 64) * 256 + tid;  // 8192 total
        int lane = idx & 63;
        int gt = (idx >> 6) & 15;
        int ks = idx >> 10;
        int col = gt * 16 + (lane & 15);
        int k0 = ks * 32 + (lane >> 4) * 8;
        const float* src = attn_W + (size_t)col * (2 * HH) + HH + k0;
        unsigned int p0 = f2bf(src[0]) | ((unsigned int)f2bf(src[1]) << 16);
        unsigned int p1 = f2bf(src[2]) | ((unsigned int)f2bf(src[3]) << 16);
        unsigned int p2 = f2bf(src[4]) | ((unsigned int)f2bf(src[5]) << 16);
        unsigned int p3 = f2bf(src[6]) | ((unsigned int)f2bf(src[7]) << 16);
        *(uint4*)(Bs + (size_t)idx * 8) = make_uint4(p0, p1, p2, p3);
    } else {
        int b = blk - 96;
        if (tid < EE) sh[tid] = emb_W[(size_t)z_tm1[b] * EE + tid];
        __syncthreads();
        if (tid < EE) {
            const float4* wrow = (const float4*)(ctrl_W + (size_t)tid * EE);
            float acc = ctrl_b[tid] + sh[tid];
            for (int k4 = 0; k4 < EE / 4; ++k4) {
                float4 w = wrow[k4];
                acc += sh[k4*4+0]*w.x + sh[k4*4+1]*w.y + sh[k4*4+2]*w.z + sh[k4*4+3]*w.w;
            }
            embed[b * EE + tid] = acc;
        }
    }
}

// ---------- K2: scores via bf16 MFMA. block=(t-chunk, b); scores out layout [b][t] ----------
__global__ __launch_bounds__(256) void k_scores_mfma(const float* __restrict__ enc,
                                                     const unsigned short* __restrict__ Bs,
                                                     const float* __restrict__ attn_v,
                                                     const float* __restrict__ hW,
                                                     float* __restrict__ scores) {
    __shared__ uint4 AbufV[2048];      // 32 KB: 64 rows x 256 k bf16, XOR-swizzled
    __shared__ float scpart[4][64];
    unsigned char* Abuf = (unsigned char*)AbufV;

    int tchunk = blockIdx.x;
    int b = blockIdx.y;
    int t0 = tchunk * 64;
    int tid = threadIdx.x;

#pragma unroll
    for (int it = 0; it < 8; ++it) {
        int c = tid + it * 256;     // 0..2047
        int row = c >> 5;
        int kc = c & 31;
        const float* src = enc + ((size_t)(t0 + row) * BB + b) * HH + kc * 8;
        float4 f0 = *(const float4*)src;
        float4 f1 = *(const float4*)(src + 4);
        unsigned int p0 = f2bf(f0.x) | ((unsigned int)f2bf(f0.y) << 16);
        unsigned int p1 = f2bf(f0.z) | ((unsigned int)f2bf(f0.w) << 16);
        unsigned int p2 = f2bf(f1.x) | ((unsigned int)f2bf(f1.y) << 16);
        unsigned int p3 = f2bf(f1.z) | ((unsigned int)f2bf(f1.w) << 16);
        int addr = (row * 512 + kc * 16) ^ ((row & 7) << 4);
        *(uint4*)(Abuf + addr) = make_uint4(p0, p1, p2, p3);
    }
    __syncthreads();

    int w = tid >> 6, lane = tid & 63;
    int lrow = lane & 15, q = lane >> 4;

    f32x4 acc[4][4];
#pragma unroll
    for (int rt = 0; rt < 4; ++rt)
#pragma unroll
        for (int ct = 0; ct < 4; ++ct) acc[rt][ct] = (f32x4){0.f, 0.f, 0.f, 0.f};

    const bf16x8* BsV = (const bf16x8*)Bs;
    for (int ks = 0; ks < 8; ++ks) {
        bf16x8 bfr[4];
        const bf16x8* bsrc = BsV + ((size_t)(ks * 16 + w * 4) * 64 + lane);
#pragma unroll
        for (int ct = 0; ct < 4; ++ct) bfr[ct] = bsrc[ct * 64];
        bf16x8 afr[4];
#pragma unroll
        for (int rt = 0; rt < 4; ++rt) {
            int arow = rt * 16 + lrow;
            int abyte = (arow * 512 + ks * 64 + q * 16) ^ ((arow & 7) << 4);
            afr[rt] = *(const bf16x8*)(Abuf + abyte);
        }
#pragma unroll
        for (int rt = 0; rt < 4; ++rt)
#pragma unroll
            for (int ct = 0; ct < 4; ++ct)
                acc[rt][ct] = __builtin_amdgcn_mfma_f32_16x16x32_bf16(afr[rt], bfr[ct], acc[rt][ct], 0, 0, 0);
    }

    float vv[4], hwv[4];
#pragma unroll
    for (int ct = 0; ct < 4; ++ct) {
        int col = w * 64 + ct * 16 + lrow;
        vv[ct] = attn_v[col];
        hwv[ct] = hW[(size_t)b * HH + col];
    }
#pragma unroll
    for (int rt = 0; rt < 4; ++rt) {
        float ps[4];
#pragma unroll
        for (int r = 0; r < 4; ++r) {
            float s = 0.f;
#pragma unroll
            for (int ct = 0; ct < 4; ++ct)
                s += vv[ct] * tanhf(acc[rt][ct][r] + hwv[ct]);
            ps[r] = s;
        }
#pragma unroll
        for (int r = 0; r < 4; ++r) {
#pragma unroll
            for (int off = 1; off < 16; off <<= 1) ps[r] += __shfl_xor(ps[r], off, 64);
        }
        if (lrow == 0) {
#pragma unroll
            for (int r = 0; r < 4; ++r) scpart[w][rt * 16 + q * 4 + r] = ps[r];
        }
    }
    __syncthreads();
    if (tid < 64) {
        float s = scpart[0][tid] + scpart[1][tid] + scpart[2][tid] + scpart[3][tid];
        scores[(size_t)b * TT + t0 + tid] = s;
    }
}

// ---------- K3: fused per-b {softmax over T, context, hidden, gen} ----------
__global__ __launch_bounds__(512) void k_post(const float* __restrict__ enc,
                                              const float* __restrict__ scores,
                                              const float* __restrict__ embed,
                                              const float* __restrict__ last_hidden,
                                              const float* __restrict__ Whid,
                                              const float* __restrict__ bhid,
                                              const float* __restrict__ Wout,
                                              const float* __restrict__ bout,
                                              float* __restrict__ out_hidden,
                                              float* __restrict__ gen) {
    __shared__ float w[TT];          // 512
    __shared__ float red[512];
    __shared__ float fin[2 * HH + EE];  // 640
    __shared__ float hid[HH];
    int b = blockIdx.x;
    int tid = threadIdx.x;

    // softmax over scores[b][0..511]
    float s = scores[(size_t)b * TT + tid];
    red[tid] = s;
    __syncthreads();
    for (int off = 256; off; off >>= 1) {
        if (tid < off) red[tid] = fmaxf(red[tid], red[tid + off]);
        __syncthreads();
    }
    float m = red[0];
    __syncthreads();
    float e = expf(s - m);
    red[tid] = e;
    __syncthreads();
    for (int off = 256; off; off >>= 1) {
        if (tid < off) red[tid] += red[tid + off];
        __syncthreads();
    }
    float inv = 1.f / red[0];
    w[tid] = e * inv;
    __syncthreads();

    // context: tid = half*256 + h; each half sums 256 t's
    int h = tid & 255, half = tid >> 8;
    float acc = 0.f;
    const float* ep = enc + ((size_t)(half * 256) * BB + b) * HH + h;
#pragma unroll 4
    for (int t = 0; t < 256; ++t) acc += w[half * 256 + t] * ep[(size_t)t * BB * HH];
    red[tid] = acc;
    __syncthreads();

    // assemble ffnn input
    for (int j = tid; j < 2 * HH + EE; j += 512) {
        float vv;
        if (j < EE) vv = embed[b * EE + j];
        else if (j < EE + HH) vv = red[j - EE] + red[256 + (j - EE)];
        else vv = last_hidden[b * HH + (j - EE - HH)];
        fin[j] = vv;
    }
    __syncthreads();

    // hidden: o = tid&255, kh = tid>>8 handles K half [kh*320, kh*320+320)
    {
        int o = tid & 255, kh = tid >> 8;
        const float4* wrow = (const float4*)(Whid + (size_t)o * (2 * HH + EE)) + kh * 80;
        const float* fb = fin + kh * 320;
        float a2 = 0.f;
        for (int k4 = 0; k4 < 80; ++k4) {
            float4 ww = wrow[k4];
            a2 += fb[k4*4+0]*ww.x + fb[k4*4+1]*ww.y + fb[k4*4+2]*ww.z + fb[k4*4+3]*ww.w;
        }
        red[tid] = a2;
    }
    __syncthreads();
    if (tid < HH) {
        float hv = fmaxf(red[tid] + red[tid + 256] + bhid[tid], 0.f);
        hid[tid] = hv;
        out_hidden[(size_t)b * HH + tid] = hv;
    }
    __syncthreads();

    // gen: o = tid&127, q = tid>>7 handles K quarter [q*64, q*64+64)
    {
        int o = tid & 127, qq = tid >> 7;
        const float4* wrow = (const float4*)(Wout + (size_t)o * HH) + qq * 16;
        const float* hb = hid + qq * 64;
        float a3 = 0.f;
        for (int k4 = 0; k4 < 16; ++k4) {
            float4 ww = wrow[k4];
            a3 += hb[k4*4+0]*ww.x + hb[k4*4+1]*ww.y + hb[k4*4+2]*ww.z + hb[k4*4+3]*ww.w;
        }
        red[tid] = a3;
    }
    __syncthreads();
    if (tid < SS) {
        gen[(size_t)b * SS + tid] =
            fmaxf(red[tid] + red[tid + 128] + red[tid + 256] + red[tid + 384] + bout[tid], 0.f);
    }
}

// ---------- K4: probas rows — analytic softmax of (-0.01 + scatter) ----------
__global__ __launch_bounds__(256) void k_probas(const int* __restrict__ slot,
                                                const float* __restrict__ gen,
                                                float* __restrict__ out) {
    int l = blockIdx.x / BB;
    int b = blockIdx.x % BB;
    int tid = threadIdx.x;
    __shared__ int cols[SS];
    __shared__ float gv[SS];
    __shared__ float red[256];
    if (tid < SS) {
        cols[tid] = slot[l * SS + tid];
        gv[tid] = gen[b * SS + tid];
    }
    __syncthreads();
    float mval = -0.01f;
    bool isfirst = false;
    float merged = -0.01f;
    if (tid < SS) {
        int c = cols[tid];
        float sum = 0.f;
        int fi = SS;
        for (int s2 = 0; s2 < SS; ++s2) {
            if (cols[s2] == c) {
                sum += gv[s2];
                if (s2 < fi) fi = s2;
            }
        }
        merged = -0.01f + sum;
        mval = merged;
        isfirst = (fi == tid);
    }
    red[tid] = mval;
    __syncthreads();
    for (int off = 128; off; off >>= 1) {
        if (tid < off) red[tid] = fmaxf(red[tid], red[tid + off]);
        __syncthreads();
    }
    float m = red[0];
    __syncthreads();
    float ex = (isfirst) ? expf(merged - m) : 0.f;
    red[tid] = ex;
    __syncthreads();
    for (int off = 128; off; off >>= 1) {
        if (tid < off) red[tid] += red[tid + off];
        __syncthreads();
    }
    float sum_hits = red[0];
    __syncthreads();
    red[tid] = isfirst ? 1.f : 0.f;
    __syncthreads();
    for (int off = 128; off; off >>= 1) {
        if (tid < off) red[tid] += red[tid + off];
        __syncthreads();
    }
    float distinct = red[0];

    float base_e = expf(-0.01f - m);
    float denom = ((float)VV - distinct) * base_e + sum_hits;
    float inv = 1.f / denom;
    float pbase = base_e * inv;

    float* row = out + BB * HH + ((size_t)(l * BB + b)) * VV;
    float4 p4 = make_float4(pbase, pbase, pbase, pbase);
    float4* row4 = (float4*)row;
    for (int idx = tid; idx < VV / 4; idx += 256) row4[idx] = p4;
    __syncthreads();
    if (tid < SS && isfirst) row[cols[tid]] = expf(merged - m) * inv;
}

extern "C" void kernel_launch(void* const* d_in, const int* in_sizes, int n_in,
                              void* d_out, int out_size, void* d_ws, size_t ws_size,
                              hipStream_t stream) {
    const float* u_enc       = (const float*)d_in[0];
    const float* last_hidden = (const float*)d_in[1];
    const int*   z_tm1       = (const int*)d_in[2];
    const int*   slot        = (const int*)d_in[3];
    const float* emb_W       = (const float*)d_in[4];
    const float* ctrl_W      = (const float*)d_in[5];
    const float* ctrl_b      = (const float*)d_in[6];
    const float* attn_W      = (const float*)d_in[7];
    const float* attn_b      = (const float*)d_in[8];
    const float* attn_v      = (const float*)d_in[9];
    const float* Whid        = (const float*)d_in[10];
    const float* bhid        = (const float*)d_in[11];
    const float* Wout        = (const float*)d_in[12];
    const float* bout        = (const float*)d_in[13];
    float* out = (float*)d_out;
    float* ws = (float*)d_ws;

    float* scores   = ws;            // 64*512 = 32768
    float* hW       = ws + 32768;    // 16384
    float* embed    = ws + 49152;    // 8192
    float* gen      = ws + 57344;    // 8192
    unsigned short* Bs = (unsigned short*)(ws + 65536);  // 65536 bf16

    k_pre<<<160, 256, 0, stream>>>(last_hidden, attn_W, attn_b, z_tm1, emb_W, ctrl_W,
                                   ctrl_b, hW, embed, Bs);
    dim3 gs(TT / 64, BB);
    k_scores_mfma<<<gs, 256, 0, stream>>>(u_enc, Bs, attn_v, hW, scores);
    k_post<<<BB, 512, 0, stream>>>(u_enc, scores, embed, last_hidden, Whid, bhid,
                                   Wout, bout, out, gen);
    k_probas<<<LL * BB, 256, 0, stream>>>(slot, gen, out);
}

// Round 4
// 98.181 us; speedup vs baseline: 1.0889x; 1.0889x over previous
//
#include <hip/hip_runtime.h>
#include <hip/hip_bf16.h>

#define BB 64
#define TT 512
#define HH 256
#define EE 128
#define VV 32000
#define SS 128
#define LL 16

typedef __attribute__((ext_vector_type(8))) short bf16x8;
typedef __attribute__((ext_vector_type(4))) float f32x4;

static __device__ __forceinline__ unsigned short f2bf(float x) {
    unsigned int u = __float_as_uint(x);
    unsigned int r = (u + 0x7fffu + ((u >> 16) & 1u)) >> 16;
    return (unsigned short)r;
}

// tanh(x) = 1 - 2/(exp2(x*2*log2e)+1); exp2->inf/0 gives correct +-1 saturation.
static __device__ __forceinline__ float ftanh(float x) {
    float y = __builtin_amdgcn_exp2f(x * 2.885390082f);
    return 1.f - 2.f * __builtin_amdgcn_rcpf(y + 1.f);
}

// ---------- K1: fused {hW, prep_b, embed} partitioned by blockIdx ----------
__global__ __launch_bounds__(256) void k_pre(const float* __restrict__ last_hidden,
                                             const float* __restrict__ attn_W,
                                             const float* __restrict__ attn_b,
                                             const int* __restrict__ z_tm1,
                                             const float* __restrict__ emb_W,
                                             const float* __restrict__ ctrl_W,
                                             const float* __restrict__ ctrl_b,
                                             float* __restrict__ hW,
                                             float* __restrict__ embed,
                                             unsigned short* __restrict__ Bs) {
    __shared__ float sh[HH];
    int blk = blockIdx.x;
    int tid = threadIdx.x;
    if (blk < 64) {
        int b = blk, h = tid;
        sh[h] = last_hidden[b * HH + h];
        __syncthreads();
        const float4* wrow = (const float4*)(attn_W + (size_t)h * (2 * HH));
        float acc = attn_b[h];
        for (int k4 = 0; k4 < HH / 4; ++k4) {
            float4 w = wrow[k4];
            acc += sh[k4*4+0]*w.x + sh[k4*4+1]*w.y + sh[k4*4+2]*w.z + sh[k4*4+3]*w.w;
        }
        hW[b * HH + h] = acc;
    } else if (blk < 96) {
        // Bs layout: [kstep 0..7][tile 0..15][lane 0..63][8 bf16]
        // col = tile*16 + (lane&15), k = kstep*32 + (lane>>4)*8 + j
        int idx = (blk - 64) * 256 + tid;  // 8192 total
        int lane = idx & 63;
        int gt = (idx >> 6) & 15;
        int ks = idx >> 10;
        int col = gt * 16 + (lane & 15);
        int k0 = ks * 32 + (lane >> 4) * 8;
        const float* src = attn_W + (size_t)col * (2 * HH) + HH + k0;
        unsigned int p0 = f2bf(src[0]) | ((unsigned int)f2bf(src[1]) << 16);
        unsigned int p1 = f2bf(src[2]) | ((unsigned int)f2bf(src[3]) << 16);
        unsigned int p2 = f2bf(src[4]) | ((unsigned int)f2bf(src[5]) << 16);
        unsigned int p3 = f2bf(src[6]) | ((unsigned int)f2bf(src[7]) << 16);
        *(uint4*)(Bs + (size_t)idx * 8) = make_uint4(p0, p1, p2, p3);
    } else {
        int b = blk - 96;
        if (tid < EE) sh[tid] = emb_W[(size_t)z_tm1[b] * EE + tid];
        __syncthreads();
        if (tid < EE) {
            const float4* wrow = (const float4*)(ctrl_W + (size_t)tid * EE);
            float acc = ctrl_b[tid] + sh[tid];
            for (int k4 = 0; k4 < EE / 4; ++k4) {
                float4 w = wrow[k4];
                acc += sh[k4*4+0]*w.x + sh[k4*4+1]*w.y + sh[k4*4+2]*w.z + sh[k4*4+3]*w.w;
            }
            embed[b * EE + tid] = acc;
        }
    }
}

// ---------- K2: scores via bf16 MFMA, contiguous 32-row tiles ----------
// rows i = t*B+b are contiguous in enc. Block stages rows [i0, i0+32) (32 KB read,
// fully coalesced), 4 waves each own 64 cols. scores output is linear in i.
__global__ __launch_bounds__(256) void k_scores_mfma(const float* __restrict__ enc,
                                                     const unsigned short* __restrict__ Bs,
                                                     const float* __restrict__ attn_v,
                                                     const float* __restrict__ hW,
                                                     float* __restrict__ scores) {
    __shared__ uint4 AbufV[1024];      // 16 KB: 32 rows x 256 k bf16, XOR-swizzled
    __shared__ float scpart[4][32];
    unsigned char* Abuf = (unsigned char*)AbufV;

    int i0 = blockIdx.x * 32;
    int tid = threadIdx.x;

    const float4* src = (const float4*)(enc + (size_t)i0 * HH);
#pragma unroll
    for (int it = 0; it < 4; ++it) {
        int c = tid + it * 256;     // 0..1023 chunks of 16B (8 bf16)
        int row = c >> 5;
        int kc = c & 31;
        float4 f0 = src[c * 2];
        float4 f1 = src[c * 2 + 1];
        unsigned int p0 = f2bf(f0.x) | ((unsigned int)f2bf(f0.y) << 16);
        unsigned int p1 = f2bf(f0.z) | ((unsigned int)f2bf(f0.w) << 16);
        unsigned int p2 = f2bf(f1.x) | ((unsigned int)f2bf(f1.y) << 16);
        unsigned int p3 = f2bf(f1.z) | ((unsigned int)f2bf(f1.w) << 16);
        int addr = (row * 512 + kc * 16) ^ ((row & 7) << 4);
        *(uint4*)(Abuf + addr) = make_uint4(p0, p1, p2, p3);
    }
    __syncthreads();

    int wv = tid >> 6, lane = tid & 63;
    int lrow = lane & 15, q = lane >> 4;

    f32x4 acc[2][4];
#pragma unroll
    for (int rt = 0; rt < 2; ++rt)
#pragma unroll
        for (int ct = 0; ct < 4; ++ct) acc[rt][ct] = (f32x4){0.f, 0.f, 0.f, 0.f};

    const bf16x8* BsV = (const bf16x8*)Bs;
    for (int ks = 0; ks < 8; ++ks) {
        bf16x8 bfr[4];
        const bf16x8* bsrc = BsV + ((size_t)(ks * 16 + wv * 4) * 64 + lane);
#pragma unroll
        for (int ct = 0; ct < 4; ++ct) bfr[ct] = bsrc[ct * 64];
        bf16x8 afr[2];
#pragma unroll
        for (int rt = 0; rt < 2; ++rt) {
            int arow = rt * 16 + lrow;
            int abyte = (arow * 512 + ks * 64 + q * 16) ^ ((arow & 7) << 4);
            afr[rt] = *(const bf16x8*)(Abuf + abyte);
        }
#pragma unroll
        for (int rt = 0; rt < 2; ++rt)
#pragma unroll
            for (int ct = 0; ct < 4; ++ct)
                acc[rt][ct] = __builtin_amdgcn_mfma_f32_16x16x32_bf16(afr[rt], bfr[ct], acc[rt][ct], 0, 0, 0);
    }

    float vvv[4];
#pragma unroll
    for (int ct = 0; ct < 4; ++ct) vvv[ct] = attn_v[wv * 64 + ct * 16 + lrow];

#pragma unroll
    for (int rt = 0; rt < 2; ++rt) {
        float ps[4];
#pragma unroll
        for (int r = 0; r < 4; ++r) {
            int i = i0 + rt * 16 + q * 4 + r;
            int b = i & (BB - 1);
            const float* hwb = hW + (size_t)b * HH + wv * 64 + lrow;
            float s = 0.f;
#pragma unroll
            for (int ct = 0; ct < 4; ++ct)
                s += vvv[ct] * ftanh(acc[rt][ct][r] + hwb[ct * 16]);
#pragma unroll
            for (int off = 1; off < 16; off <<= 1) s += __shfl_xor(s, off, 64);
            ps[r] = s;
        }
        if (lrow == 0) {
#pragma unroll
            for (int r = 0; r < 4; ++r) scpart[wv][rt * 16 + q * 4 + r] = ps[r];
        }
    }
    __syncthreads();
    if (tid < 32) {
        float s = scpart[0][tid] + scpart[1][tid] + scpart[2][tid] + scpart[3][tid];
        scores[i0 + tid] = s;   // linear in i = t*B + b
    }
}

// ---------- K3: fused per-b {softmax over T, context, hidden, gen}, 1024 threads ----------
__global__ __launch_bounds__(1024) void k_post(const float* __restrict__ enc,
                                               const float* __restrict__ scores,
                                               const float* __restrict__ embed,
                                               const float* __restrict__ last_hidden,
                                               const float* __restrict__ Whid,
                                               const float* __restrict__ bhid,
                                               const float* __restrict__ Wout,
                                               const float* __restrict__ bout,
                                               float* __restrict__ out_hidden,
                                               float* __restrict__ gen) {
    __shared__ float w[TT];            // 512
    __shared__ float red[1024];
    __shared__ float fin[2 * HH + EE]; // 640
    __shared__ float hid[HH];
    int b = blockIdx.x;
    int tid = threadIdx.x;

    // softmax over scores[t*64 + b]
    float s = -1e30f;
    if (tid < TT) s = scores[(size_t)tid * BB + b];
    red[tid] = s;
    __syncthreads();
    for (int off = 512; off; off >>= 1) {
        if (tid < off) red[tid] = fmaxf(red[tid], red[tid + off]);
        __syncthreads();
    }
    float m = red[0];
    __syncthreads();
    float e = (tid < TT) ? expf(s - m) : 0.f;
    red[tid] = e;
    __syncthreads();
    for (int off = 512; off; off >>= 1) {
        if (tid < off) red[tid] += red[tid + off];
        __syncthreads();
    }
    float inv = 1.f / red[0];
    if (tid < TT) w[tid] = e * inv;
    __syncthreads();

    // context: qd = tid>>8 handles t in [qd*128, qd*128+128)
    int h = tid & 255, qd = tid >> 8;
    float acc = 0.f;
    const float* ep = enc + ((size_t)(qd * 128) * BB + b) * HH + h;
#pragma unroll 4
    for (int t = 0; t < 128; ++t) acc += w[qd * 128 + t] * ep[(size_t)t * BB * HH];
    red[tid] = acc;
    __syncthreads();

    // assemble ffnn input [embed(128) | ctx(256) | last_hidden(256)]
    for (int j = tid; j < 2 * HH + EE; j += 1024) {
        float vv;
        if (j < EE) vv = embed[b * EE + j];
        else if (j < EE + HH) {
            int hh = j - EE;
            vv = red[hh] + red[256 + hh] + red[512 + hh] + red[768 + hh];
        } else vv = last_hidden[b * HH + (j - EE - HH)];
        fin[j] = vv;
    }
    __syncthreads();

    // hidden: o = tid&255, kh = tid>>8 handles K chunk [kh*160, kh*160+160)
    {
        int o = tid & 255, kh = tid >> 8;
        const float4* wrow = (const float4*)(Whid + (size_t)o * (2 * HH + EE)) + kh * 40;
        const float* fb = fin + kh * 160;
        float a2 = 0.f;
        for (int k4 = 0; k4 < 40; ++k4) {
            float4 ww = wrow[k4];
            a2 += fb[k4*4+0]*ww.x + fb[k4*4+1]*ww.y + fb[k4*4+2]*ww.z + fb[k4*4+3]*ww.w;
        }
        red[tid] = a2;
    }
    __syncthreads();
    if (tid < HH) {
        float hv = fmaxf(red[tid] + red[tid + 256] + red[tid + 512] + red[tid + 768] + bhid[tid], 0.f);
        hid[tid] = hv;
        out_hidden[(size_t)b * HH + tid] = hv;
    }
    __syncthreads();

    // gen: o = tid&127, q8 = tid>>7 handles K chunk [q8*32, q8*32+32)
    {
        int o = tid & 127, q8 = tid >> 7;
        const float4* wrow = (const float4*)(Wout + (size_t)o * HH) + q8 * 8;
        const float* hb = hid + q8 * 32;
        float a3 = 0.f;
        for (int k4 = 0; k4 < 8; ++k4) {
            float4 ww = wrow[k4];
            a3 += hb[k4*4+0]*ww.x + hb[k4*4+1]*ww.y + hb[k4*4+2]*ww.z + hb[k4*4+3]*ww.w;
        }
        red[tid] = a3;
    }
    __syncthreads();
    if (tid < SS) {
        float g = bout[tid];
#pragma unroll
        for (int j = 0; j < 8; ++j) g += red[tid + j * 128];
        gen[(size_t)b * SS + tid] = fmaxf(g, 0.f);
    }
}

// ---------- K4: probas rows — analytic softmax of (-0.01 + scatter) ----------
__global__ __launch_bounds__(256) void k_probas(const int* __restrict__ slot,
                                                const float* __restrict__ gen,
                                                float* __restrict__ out) {
    int l = blockIdx.x / BB;
    int b = blockIdx.x % BB;
    int tid = threadIdx.x;
    __shared__ int cols[SS];
    __shared__ float gv[SS];
    __shared__ float red[256];
    if (tid < SS) {
        cols[tid] = slot[l * SS + tid];
        gv[tid] = gen[b * SS + tid];
    }
    __syncthreads();
    float mval = -0.01f;
    bool isfirst = false;
    float merged = -0.01f;
    if (tid < SS) {
        int c = cols[tid];
        float sum = 0.f;
        int fi = SS;
        for (int s2 = 0; s2 < SS; ++s2) {
            if (cols[s2] == c) {
                sum += gv[s2];
                if (s2 < fi) fi = s2;
            }
        }
        merged = -0.01f + sum;
        mval = merged;
        isfirst = (fi == tid);
    }
    red[tid] = mval;
    __syncthreads();
    for (int off = 128; off; off >>= 1) {
        if (tid < off) red[tid] = fmaxf(red[tid], red[tid + off]);
        __syncthreads();
    }
    float m = red[0];
    __syncthreads();
    float ex = (isfirst) ? expf(merged - m) : 0.f;
    red[tid] = ex;
    __syncthreads();
    for (int off = 128; off; off >>= 1) {
        if (tid < off) red[tid] += red[tid + off];
        __syncthreads();
    }
    float sum_hits = red[0];
    __syncthreads();
    red[tid] = isfirst ? 1.f : 0.f;
    __syncthreads();
    for (int off = 128; off; off >>= 1) {
        if (tid < off) red[tid] += red[tid + off];
        __syncthreads();
    }
    float distinct = red[0];

    float base_e = expf(-0.01f - m);
    float denom = ((float)VV - distinct) * base_e + sum_hits;
    float inv = 1.f / denom;
    float pbase = base_e * inv;

    float* row = out + BB * HH + ((size_t)(l * BB + b)) * VV;
    float4 p4 = make_float4(pbase, pbase, pbase, pbase);
    float4* row4 = (float4*)row;
    for (int idx = tid; idx < VV / 4; idx += 256) row4[idx] = p4;
    __syncthreads();
    if (tid < SS && isfirst) row[cols[tid]] = expf(merged - m) * inv;
}

extern "C" void kernel_launch(void* const* d_in, const int* in_sizes, int n_in,
                              void* d_out, int out_size, void* d_ws, size_t ws_size,
                              hipStream_t stream) {
    const float* u_enc       = (const float*)d_in[0];
    const float* last_hidden = (const float*)d_in[1];
    const int*   z_tm1       = (const int*)d_in[2];
    const int*   slot        = (const int*)d_in[3];
    const float* emb_W       = (const float*)d_in[4];
    const float* ctrl_W      = (const float*)d_in[5];
    const float* ctrl_b      = (const float*)d_in[6];
    const float* attn_W      = (const float*)d_in[7];
    const float* attn_b      = (const float*)d_in[8];
    const float* attn_v      = (const float*)d_in[9];
    const float* Whid        = (const float*)d_in[10];
    const float* bhid        = (const float*)d_in[11];
    const float* Wout        = (const float*)d_in[12];
    const float* bout        = (const float*)d_in[13];
    float* out = (float*)d_out;
    float* ws = (float*)d_ws;

    float* scores   = ws;            // 32768 (linear i = t*B + b)
    float* hW       = ws + 32768;    // 16384
    float* embed    = ws + 49152;    // 8192
    float* gen      = ws + 57344;    // 8192
    unsigned short* Bs = (unsigned short*)(ws + 65536);  // 65536 bf16

    k_pre<<<160, 256, 0, stream>>>(last_hidden, attn_W, attn_b, z_tm1, emb_W, ctrl_W,
                                   ctrl_b, hW, embed, Bs);
    k_scores_mfma<<<(TT * BB) / 32, 256, 0, stream>>>(u_enc, Bs, attn_v, hW, scores);
    k_post<<<BB, 1024, 0, stream>>>(u_enc, scores, embed, last_hidden, Whid, bhid,
                                    Wout, bout, out, gen);
    k_probas<<<LL * BB, 256, 0, stream>>>(slot, gen, out);
}